// Round 5
// baseline (99.902 us; speedup 1.0000x reference)
//
#include <hip/hip_runtime.h>

// Problem constants (from reference setup_inputs)
#define Bn 8
#define Nn 128
#define Fdim 32     // input feature dim F
#define Sdim 8      // edge feature dim S
#define Hdim 32     // kernel-network hidden width H
#define Fout 32     // output channels F_

typedef float  f32x4  __attribute__((ext_vector_type(4)));
typedef short  bf16x8 __attribute__((ext_vector_type(8)));

#define PITCH 136   // bf16 row pitch for hT/nT: 272B = 17*16B (aligned, bank-spread)
#define TSP   36    // f32 row pitch for Ts (16B-aligned rows, bank-spread)

__device__ __forceinline__ unsigned short f2bf(float x) {
    union { float f; unsigned u; } v; v.f = x;
    return (unsigned short)((v.u + 0x7FFFu + ((v.u >> 16) & 1u)) >> 16);
}
__device__ __forceinline__ unsigned pack2(float lo, float hi) {
    return (unsigned)f2bf(lo) | ((unsigned)f2bf(hi) << 16);
}

// One block per (a,b); 512 threads (8 waves); 2 barriers.
// out[a,b,c] = inv * ( sum_{h,f} T'[h,f]*Wout[h,c*32+f] + sum_f q'[f]*bout[c*32+f] ) + bias[c]
//   T'[h,f] = sum_i fltr[i]*relu(ef[a,b,i,:]@W0+b0)[h]*nf[a,i,f]   (bf16 MFMA, f32 accum)
//   q'[f]   = sum_i fltr[i]*nf[a,i,f]
//   inv     = 1/max(sum_i fltr[i], 1e-11)
__global__ __launch_bounds__(512, 8) void ecc_kernel(
    const float* __restrict__ nf,    // (B,N,F)
    const float* __restrict__ fltr,  // (B,N,N)
    const float* __restrict__ ef,    // (B,N,N,S)
    const float* __restrict__ W0,    // (S,H)
    const float* __restrict__ b0,    // (H)
    const float* __restrict__ Wout,  // (H, F_*F)
    const float* __restrict__ bout,  // (F_*F)
    const float* __restrict__ bias,  // (F_)
    float* __restrict__ out)         // (B,N,F_)
{
    __shared__ __align__(16) unsigned short hT[Hdim * PITCH];  // h^T[h][i] bf16 (fltr-scaled relu)
    __shared__ __align__(16) unsigned short nT[Fdim * PITCH];  // nf^T[f][i] bf16
    __shared__ __align__(16) float Ts[Hdim * TSP];             // T'[h][f] f32 (ds_add-merged)
    __shared__ __align__(16) float qp[16 * Fdim];              // q partials (16 i-segs x 32 f)
    __shared__ float inv_s;

    const int t    = threadIdx.x;
    const int blk  = blockIdx.x;       // a*N + b
    const int a    = blk >> 7;
    const int hcol = t & 31;           // h (phase A) / f (nT+qp)
    const int seg  = t >> 5;           // i-segment 0..15 (8 i's each)

    const float* __restrict__ nfa  = nf   + (size_t)a   * (Nn * Fdim);
    const float* __restrict__ frow = fltr + (size_t)blk * Nn;
    const float* __restrict__ erow = ef   + (size_t)blk * (Nn * Sdim);

    // ---- W0 column + b0 in registers ----
    float w0r[Sdim];
    #pragma unroll
    for (int s = 0; s < Sdim; ++s) w0r[s] = W0[s * Hdim + hcol];
    const float b0r = b0[hcol];

    // ---- inv = 1/sum(fltr row)  (wave 0; visible at B1) ----
    if (t < 64) {
        float s = frow[t] + frow[t + 64];
        #pragma unroll
        for (int off = 32; off > 0; off >>= 1) s += __shfl_down(s, off);
        if (t == 0) inv_s = 1.0f / fmaxf(s, 1e-11f);
    }

    // ---- zero Ts (ds_add target) ----
    if (t < (Hdim * TSP) / 4) ((f32x4*)Ts)[t] = (f32x4){0.f, 0.f, 0.f, 0.f};

    // ---- nf^T stage (bf16) fused with q' partials: one global read feeds both ----
    {
        float x[8], q = 0.f;
        #pragma unroll
        for (int k = 0; k < 8; ++k) {
            const int i = seg * 8 + k;
            x[k] = nfa[i * Fdim + hcol];          // lanes f=0..31 -> coalesced 128B
            q += frow[i] * x[k];
        }
        unsigned* dst = (unsigned*)&nT[hcol * PITCH + seg * 8];
        #pragma unroll
        for (int k = 0; k < 8; k += 2) dst[k >> 1] = pack2(x[k], x[k + 1]);
        qp[seg * Fdim + hcol] = q;
    }

    // ---- h^T: hT[h][i] = bf16( relu(ef[i,:]@W0+b0)[h] * fltr[i] ), 8 i per thread ----
    {
        unsigned* dst = (unsigned*)&hT[hcol * PITCH + seg * 8];
        #pragma unroll 4
        for (int k = 0; k < 8; k += 2) {
            const int i0 = seg * 8 + k;
            const float4 e0a = *(const float4*)(erow + i0 * Sdim);
            const float4 e0b = *(const float4*)(erow + i0 * Sdim + 4);
            const float4 e1a = *(const float4*)(erow + i0 * Sdim + 8);
            const float4 e1b = *(const float4*)(erow + i0 * Sdim + 12);
            float a0 = b0r, a1 = b0r;
            a0 += e0a.x * w0r[0] + e0a.y * w0r[1] + e0a.z * w0r[2] + e0a.w * w0r[3];
            a0 += e0b.x * w0r[4] + e0b.y * w0r[5] + e0b.z * w0r[6] + e0b.w * w0r[7];
            a1 += e1a.x * w0r[0] + e1a.y * w0r[1] + e1a.z * w0r[2] + e1a.w * w0r[3];
            a1 += e1b.x * w0r[4] + e1b.y * w0r[5] + e1b.z * w0r[6] + e1b.w * w0r[7];
            const float h0 = fmaxf(a0, 0.0f) * frow[i0];
            const float h1 = fmaxf(a1, 0.0f) * frow[i0 + 1];
            dst[k >> 1] = pack2(h0, h1);
        }
    }
    __syncthreads();                                   // B1

    // ---- T' via MFMA: 4 tiles x 2 K-halves across 8 waves; ds_add merge ----
    {
        const int w  = t >> 6, l = t & 63;
        const int lr = l & 15, lg = l >> 4;
        const int tile = w & 3, kh = w >> 2;
        const int mt = tile >> 1, nt = tile & 1;
        f32x4 acc = {0.f, 0.f, 0.f, 0.f};
        #pragma unroll
        for (int kk = 0; kk < 2; ++kk) {
            const int kt = kh * 2 + kk;
            const bf16x8 av = *(const bf16x8*)&hT[(mt * 16 + lr) * PITCH + kt * 32 + lg * 8];
            const bf16x8 bv = *(const bf16x8*)&nT[(nt * 16 + lr) * PITCH + kt * 32 + lg * 8];
            acc = __builtin_amdgcn_mfma_f32_16x16x32_bf16(av, bv, acc, 0, 0, 0);
        }
        // C/D layout: col = lane&15, row = (lane>>4)*4 + reg   [m89-verified]
        #pragma unroll
        for (int r = 0; r < 4; ++r)
            atomicAdd(&Ts[(mt * 16 + lg * 4 + r) * TSP + nt * 16 + lr], acc[r]);
    }
    __syncthreads();                                   // B2

    // ---- epilogue: out[c] = inv*(Ts.Wout + q'.bout) + bias ----
    // thread (c = t>>4, hp = t&15): h in {hp, hp+16}; q-seg = hp; 16-lane shfl reduce
    {
        const int c = t >> 4, hp = t & 15;
        float partial = 0.f;
        #pragma unroll
        for (int hh = 0; hh < 2; ++hh) {
            const int h = hp + hh * 16;
            const float* wbase = Wout + (size_t)h * (Fout * Fdim) + c * Fdim;
            #pragma unroll 4
            for (int f4 = 0; f4 < 8; ++f4) {
                const float4 wv = *(const float4*)(wbase + f4 * 4);
                const float4 tv = *(const float4*)&Ts[h * TSP + f4 * 4];
                partial += tv.x * wv.x + tv.y * wv.y + tv.z * wv.z + tv.w * wv.w;
            }
        }
        {
            const float* bbase = bout + (size_t)c * Fdim;
            #pragma unroll 4
            for (int f4 = 0; f4 < 8; ++f4) {
                const float4 bv = *(const float4*)(bbase + f4 * 4);
                const float4 qv = *(const float4*)&qp[hp * Fdim + f4 * 4];
                partial += qv.x * bv.x + qv.y * bv.y + qv.z * bv.z + qv.w * bv.w;
            }
        }
        partial += __shfl_down(partial, 8, 16);
        partial += __shfl_down(partial, 4, 16);
        partial += __shfl_down(partial, 2, 16);
        partial += __shfl_down(partial, 1, 16);
        if (hp == 0)
            out[(size_t)blk * Fout + c] = partial * inv_s + bias[c];
    }
}

extern "C" void kernel_launch(void* const* d_in, const int* in_sizes, int n_in,
                              void* d_out, int out_size, void* d_ws, size_t ws_size,
                              hipStream_t stream) {
    const float* nf   = (const float*)d_in[0];
    const float* fltr = (const float*)d_in[1];
    const float* ef   = (const float*)d_in[2];
    const float* W0   = (const float*)d_in[3];
    const float* b0   = (const float*)d_in[4];
    const float* Wout = (const float*)d_in[5];
    const float* bout = (const float*)d_in[6];
    const float* bias = (const float*)d_in[7];
    float* out = (float*)d_out;

    ecc_kernel<<<dim3(Bn * Nn), dim3(512), 0, stream>>>(
        nf, fltr, ef, W0, b0, Wout, bout, bias, out);
}

// Round 7
// 88.663 us; speedup vs baseline: 1.1268x; 1.1268x over previous
//
#include <hip/hip_runtime.h>

// Problem constants (from reference setup_inputs)
#define Bn 8
#define Nn 128
#define Fdim 32     // input feature dim F
#define Sdim 8      // edge feature dim S
#define Hdim 32     // kernel-network hidden width H
#define Fout 32     // output channels F_

#define PITCH  72   // bf16 elems per hT/nT row (K=64 + pad) -> 144B, 16B-aligned, bank-spread
#define ROWLEN 1056 // f32 elems per partial row: 1024 (h*32+f) + 32 (q')
#define ROW2   2112 // both K-halves

typedef float  f32x4  __attribute__((ext_vector_type(4)));
typedef short  bf16x8 __attribute__((ext_vector_type(8)));

__device__ __forceinline__ unsigned short f2bf(float x) {
    union { float f; unsigned u; } v; v.f = x;
    return (unsigned short)((v.u + 0x7FFFu + ((v.u >> 16) & 1u)) >> 16);
}
__device__ __forceinline__ unsigned pack2(float lo, float hi) {
    return (unsigned)f2bf(lo) | ((unsigned)f2bf(hi) << 16);
}

// ---------------- K1: per (a,b,khalf) partial rows ----------------
// P[ab][kh][k] = inv * sum_{i in half} fltr[i]*relu(ef[i,:]@W0+b0)[h]*nf[a,i,f],  k=h*32+f
// P[ab][kh][1024+f] = inv * sum_{i in half} fltr[i]*nf[a,i,f]
__global__ __launch_bounds__(256, 4) void ecc_k1(
    const float* __restrict__ nf,    // (B,N,F)
    const float* __restrict__ fltr,  // (B,N,N)
    const float* __restrict__ ef,    // (B,N,N,S)
    const float* __restrict__ W0,    // (S,H)
    const float* __restrict__ b0,    // (H)
    float* __restrict__ P)           // ws: (1024, 2, 1056) f32
{
    __shared__ __align__(16) unsigned short hT[Hdim * PITCH]; // h^T[h][li] bf16 (fltr-scaled relu)
    __shared__ __align__(16) unsigned short nT[Fdim * PITCH]; // nf^T[f][li] bf16
    __shared__ float qp[8 * Fdim];
    __shared__ float inv_s;

    const int t     = threadIdx.x;
    const int blk   = blockIdx.x;      // ab*2 + kh
    const int ab    = blk >> 1, kh = blk & 1;
    const int a     = ab >> 7;
    const int i0    = kh * 64;
    const int lane5 = t & 31;          // h (hT) / f (nT)
    const int seg   = t >> 5;          // 8 segments x 8 i's

    const float* __restrict__ nfa  = nf   + (size_t)a  * (Nn * Fdim);
    const float* __restrict__ frow = fltr + (size_t)ab * Nn;
    const float* __restrict__ erow = ef   + (size_t)ab * (Nn * Sdim);

    float w0r[Sdim];
    #pragma unroll
    for (int s = 0; s < Sdim; ++s) w0r[s] = W0[s * Hdim + lane5];
    const float b0r = b0[lane5];

    // inv = 1/sum(full fltr row)  (wave 0, pre-barrier; consumed post-barrier)
    if (t < 64) {
        float s = frow[t] + frow[t + 64];
        #pragma unroll
        for (int off = 32; off > 0; off >>= 1) s += __shfl_down(s, off);
        if (t == 0) inv_s = 1.0f / fmaxf(s, 1e-11f);
    }

    // nf^T staging (bf16) fused with q partial
    {
        float x[8], q = 0.f;
        #pragma unroll
        for (int k = 0; k < 8; ++k) {
            const int i = i0 + seg * 8 + k;
            x[k] = nfa[i * Fdim + lane5];          // coalesced 128B across lanes
            q += frow[i] * x[k];
        }
        unsigned* dst = (unsigned*)&nT[lane5 * PITCH + seg * 8];
        #pragma unroll
        for (int k = 0; k < 8; k += 2) dst[k >> 1] = pack2(x[k], x[k + 1]);
        qp[seg * Fdim + lane5] = q;
    }

    // h^T staging: hT[h][li] = bf16( relu(ef[i,:]@W0+b0)[h] * fltr[i] )
    {
        unsigned* dst = (unsigned*)&hT[lane5 * PITCH + seg * 8];
        #pragma unroll
        for (int k = 0; k < 8; k += 2) {
            const int i = i0 + seg * 8 + k;
            const float4 e0a = *(const float4*)(erow + i * Sdim);
            const float4 e0b = *(const float4*)(erow + i * Sdim + 4);
            const float4 e1a = *(const float4*)(erow + i * Sdim + 8);
            const float4 e1b = *(const float4*)(erow + i * Sdim + 12);
            float a0 = b0r, a1 = b0r;
            a0 += e0a.x * w0r[0] + e0a.y * w0r[1] + e0a.z * w0r[2] + e0a.w * w0r[3];
            a0 += e0b.x * w0r[4] + e0b.y * w0r[5] + e0b.z * w0r[6] + e0b.w * w0r[7];
            a1 += e1a.x * w0r[0] + e1a.y * w0r[1] + e1a.z * w0r[2] + e1a.w * w0r[3];
            a1 += e1b.x * w0r[4] + e1b.y * w0r[5] + e1b.z * w0r[6] + e1b.w * w0r[7];
            const float h0 = fmaxf(a0, 0.0f) * frow[i];
            const float h1 = fmaxf(a1, 0.0f) * frow[i + 1];
            dst[k >> 1] = pack2(h0, h1);
        }
    }
    __syncthreads();                                 // only barrier

    // T-partial via MFMA: 4 waves x one 16x16 tile, K=64 (2 steps)
    {
        const int w  = t >> 6, l = t & 63;
        const int lr = l & 15, lg = l >> 4;
        const int mt = w >> 1, nt = w & 1;
        f32x4 acc = {0.f, 0.f, 0.f, 0.f};
        #pragma unroll
        for (int kt = 0; kt < 2; ++kt) {
            const bf16x8 av = *(const bf16x8*)&hT[(mt * 16 + lr) * PITCH + kt * 32 + lg * 8];
            const bf16x8 bv = *(const bf16x8*)&nT[(nt * 16 + lr) * PITCH + kt * 32 + lg * 8];
            acc = __builtin_amdgcn_mfma_f32_16x16x32_bf16(av, bv, acc, 0, 0, 0);
        }
        // C/D: col = lane&15, row = (lane>>4)*4 + reg  [m89-verified]
        const float inv = inv_s;
        float* prow = P + (size_t)ab * ROW2 + (size_t)kh * ROWLEN;
        #pragma unroll
        for (int r = 0; r < 4; ++r)
            prow[(mt * 16 + lg * 4 + r) * 32 + nt * 16 + lr] = acc[r] * inv;
    }
    // q' reduce (32 threads), k = 1024..1055
    if (t < 32) {
        float q = 0.f;
        #pragma unroll
        for (int s = 0; s < 8; ++s) q += qp[s * Fdim + t];
        P[(size_t)ab * ROW2 + (size_t)kh * ROWLEN + 1024 + t] = q * inv_s;
    }
}

// ---------------- K2: out = bf16(P0+P1) @ W2 + bias ----------------
// M=1024 (ab), N=32 (c), K=1056. W2[k][c] = Wout[k>>5][c*32+(k&31)] for k<1024, else bout[c*32+(k&31)].
// 64 blocks (16 M-rows each) x 4 waves (K-chunks {9,8,8,8} of 33 k-steps), LDS merge.
__global__ __launch_bounds__(256) void ecc_k2(
    const float* __restrict__ P,     // (1024, 2, 1056) f32
    const float* __restrict__ Wout,  // (H, F_*F) = (32, 1024)
    const float* __restrict__ bout,  // (1024)
    const float* __restrict__ bias,  // (32)
    float* __restrict__ out)         // (B,N,F_) = (1024, 32)
{
    __shared__ __align__(16) float pbuf[4 * 512];

    const int t  = threadIdx.x;
    const int w  = t >> 6, l = t & 63;
    const int lr = l & 15, lg = l >> 4;
    const int mtile = blockIdx.x;

    const float* arow = P + (size_t)(mtile * 16 + lr) * ROW2;
    const int ks = (w == 0) ? 0 : (8 * w + 1);
    const int ke = 8 * w + 9;

    f32x4 acc0 = {0.f, 0.f, 0.f, 0.f};
    f32x4 acc1 = {0.f, 0.f, 0.f, 0.f};

    for (int kt = ks; kt < ke; ++kt) {
        const int k0 = kt * 32 + lg * 8;
        // A: sum the two K-half partials, convert to bf16
        const float4 a0 = *(const float4*)(arow + k0);
        const float4 a1 = *(const float4*)(arow + k0 + 4);
        const float4 a2 = *(const float4*)(arow + ROWLEN + k0);
        const float4 a3 = *(const float4*)(arow + ROWLEN + k0 + 4);
        union { bf16x8 v; unsigned u[4]; } av;
        av.u[0] = pack2(a0.x + a2.x, a0.y + a2.y);
        av.u[1] = pack2(a0.z + a2.z, a0.w + a2.w);
        av.u[2] = pack2(a1.x + a3.x, a1.y + a3.y);
        av.u[3] = pack2(a1.z + a3.z, a1.w + a3.w);
        // B: W2 rows read with natural contiguity (8 consecutive k = 8 consecutive f)
        const float* wb = (kt < 32) ? (Wout + (size_t)kt * (Fout * Fdim)) : bout;
        {
            const float* p = wb + lr * Fdim + lg * 8;          // c = lr
            const float4 b0v = *(const float4*)p;
            const float4 b1v = *(const float4*)(p + 4);
            union { bf16x8 v; unsigned u[4]; } bv;
            bv.u[0] = pack2(b0v.x, b0v.y); bv.u[1] = pack2(b0v.z, b0v.w);
            bv.u[2] = pack2(b1v.x, b1v.y); bv.u[3] = pack2(b1v.z, b1v.w);
            acc0 = __builtin_amdgcn_mfma_f32_16x16x32_bf16(av.v, bv.v, acc0, 0, 0, 0);
        }
        {
            const float* p = wb + (16 + lr) * Fdim + lg * 8;   // c = 16 + lr
            const float4 b0v = *(const float4*)p;
            const float4 b1v = *(const float4*)(p + 4);
            union { bf16x8 v; unsigned u[4]; } bv;
            bv.u[0] = pack2(b0v.x, b0v.y); bv.u[1] = pack2(b0v.z, b0v.w);
            bv.u[2] = pack2(b1v.x, b1v.y); bv.u[3] = pack2(b1v.z, b1v.w);
            acc1 = __builtin_amdgcn_mfma_f32_16x16x32_bf16(av.v, bv.v, acc1, 0, 0, 0);
        }
    }

    // park partials: pbuf[w][(row_in_tile)*32 + c]
    #pragma unroll
    for (int r = 0; r < 4; ++r) {
        pbuf[w * 512 + (lg * 4 + r) * 32 + lr]      = acc0[r];
        pbuf[w * 512 + (lg * 4 + r) * 32 + 16 + lr] = acc1[r];
    }
    __syncthreads();

    #pragma unroll
    for (int e = t; e < 512; e += 256) {
        const int m = e >> 5, c = e & 31;
        const float s = pbuf[e] + pbuf[512 + e] + pbuf[1024 + e] + pbuf[1536 + e] + bias[c];
        out[(size_t)(mtile * 16 + m) * Fout + c] = s;
    }
}

extern "C" void kernel_launch(void* const* d_in, const int* in_sizes, int n_in,
                              void* d_out, int out_size, void* d_ws, size_t ws_size,
                              hipStream_t stream) {
    const float* nf   = (const float*)d_in[0];
    const float* fltr = (const float*)d_in[1];
    const float* ef   = (const float*)d_in[2];
    const float* W0   = (const float*)d_in[3];
    const float* b0   = (const float*)d_in[4];
    const float* Wout = (const float*)d_in[5];
    const float* bout = (const float*)d_in[6];
    const float* bias = (const float*)d_in[7];
    float* out = (float*)d_out;
    float* P   = (float*)d_ws;   // 1024*2*1056 f32 = 8.65 MB

    ecc_k1<<<dim3(Bn * Nn * 2), dim3(256), 0, stream>>>(nf, fltr, ef, W0, b0, P);
    ecc_k2<<<dim3(64), dim3(256), 0, stream>>>(P, Wout, bout, bias, out);
}